// Round 6
// baseline (282.618 us; speedup 1.0000x reference)
//
#include <hip/hip_runtime.h>
#include <hip/hip_bf16.h>

// B=2, T=2048, E=1024, H=16, D=64. Inputs f32 (+ int32 mask), output f32.
// Internal bf16 MFMA pipeline. Flash: S^T formulation, fixed-max exp2
// softmax, q-tile 128, KEY-SPLIT x2 across blocks (linear partial combine —
// valid only because softmax max is fixed), single-buffered reg-staged LDS,
// prefetch between the two barriers. 34.8KB LDS -> 4 blocks/CU = 32 waves.

typedef __bf16 bf8_t  __attribute__((ext_vector_type(8)));
typedef __bf16 bf4_t  __attribute__((ext_vector_type(4)));
typedef float  f4_t   __attribute__((ext_vector_type(4)));

constexpr int Bb = 2, Tt = 2048, Hh = 16, Dd = 64;

#define ASYNC16(g, l)                                                        \
    __builtin_amdgcn_global_load_lds(                                        \
        (const __attribute__((address_space(1))) void*)(g),                  \
        (__attribute__((address_space(3))) void*)(l), 16, 0, 0)

#if __has_builtin(__builtin_amdgcn_exp2f)
#define EXP2F(x) __builtin_amdgcn_exp2f(x)
#else
#define EXP2F(x) exp2f(x)
#endif

// ------------------------------------------------------------ f32 -> bf16
__global__ __launch_bounds__(256) void convert_kernel(
    const float* __restrict__ in, __bf16* __restrict__ out)
{
    int i = (blockIdx.x * 256 + threadIdx.x) * 4;
    float4 v = *reinterpret_cast<const float4*>(in + i);
    bf4_t o = {(__bf16)v.x, (__bf16)v.y, (__bf16)v.z, (__bf16)v.w};
    *reinterpret_cast<bf4_t*>(out + i) = o;
}

// ------------------------------------------------------ mask -> bf16 bias
__global__ __launch_bounds__(256) void maskbias_kernel(
    const int* __restrict__ m, __bf16* __restrict__ o)
{
    int i = (blockIdx.x * 256 + threadIdx.x) * 4;
    int4 v = *reinterpret_cast<const int4*>(m + i);
    const __bf16 z = (__bf16)0.f, neg = (__bf16)(-1e30f);
    bf4_t r = {v.x ? z : neg, v.y ? z : neg, v.z ? z : neg, v.w ? z : neg};
    *reinterpret_cast<bf4_t*>(o + i) = r;
}

// ------------------------------------------------------------ transpose+cast
__global__ __launch_bounds__(256) void transpose_kernel(
    const float* __restrict__ w0, const float* __restrict__ w1,
    const float* __restrict__ w2, const float* __restrict__ w3,
    __bf16* __restrict__ o0, __bf16* __restrict__ o1,
    __bf16* __restrict__ o2, __bf16* __restrict__ o3)
{
    const float* in; __bf16* out;
    switch (blockIdx.z) {
        case 0: in = w0; out = o0; break;
        case 1: in = w1; out = o1; break;
        case 2: in = w2; out = o2; break;
        default: in = w3; out = o3; break;
    }
    __shared__ float t[32][33];
    int x  = threadIdx.x & 31;
    int y0 = threadIdx.x >> 5;
    int bx = blockIdx.x * 32;
    int by = blockIdx.y * 32;
    #pragma unroll
    for (int i = 0; i < 4; i++) {
        int y = y0 + i * 8;
        t[y][x] = in[(size_t)(by + y) * 1024 + bx + x];
    }
    __syncthreads();
    #pragma unroll
    for (int i = 0; i < 4; i++) {
        int y = y0 + i * 8;
        out[(size_t)(bx + y) * 1024 + by + x] = (__bf16)t[x][y];
    }
}

// ---------------------------------------------------------------- GEMM body
// (unchanged — known good)
template <int TM, typename OutT>
__device__ __forceinline__ void gemm_body(const __bf16* __restrict__ A,
                                          const __bf16* __restrict__ Bt,
                                          const float* __restrict__ bias,
                                          OutT* __restrict__ out,
                                          int mode, float oscale, int bx, int by)
{
    constexpr int NI = TM / 32;
    alignas(16) __shared__ __bf16 As[TM * 64];
    alignas(16) __shared__ __bf16 Bs[128 * 64];

    int tid  = threadIdx.x;
    int lane = tid & 63;
    int quad = lane >> 4;
    int l16  = lane & 15;
    int wave = tid >> 6;
    int wm   = wave >> 1, wn = wave & 1;

    f4_t acc[NI][4];
    #pragma unroll
    for (int i = 0; i < NI; i++)
        #pragma unroll
        for (int j = 0; j < 4; j++)
            acc[i][j] = f4_t{0.f, 0.f, 0.f, 0.f};

    for (int kt = 0; kt < 1024; kt += 64) {
        #pragma unroll
        for (int i = 0; i < TM / 32; i++) {
            int c   = tid + 256 * i;
            int row = c >> 3, j = c & 7;
            ASYNC16(A + (size_t)(by * TM + row) * 1024 + kt + ((j ^ (row & 7)) * 8),
                    &As[c * 8]);
        }
        #pragma unroll
        for (int i = 0; i < 4; i++) {
            int c   = tid + 256 * i;
            int row = c >> 3, j = c & 7;
            ASYNC16(Bt + (size_t)(bx * 128 + row) * 1024 + kt + ((j ^ (row & 7)) * 8),
                    &Bs[c * 8]);
        }
        __syncthreads();

        bf8_t af[2][NI], bfr[2][4];
        #pragma unroll
        for (int c = 0; c < 2; c++) {
            #pragma unroll
            for (int im = 0; im < NI; im++) {
                int row = wm * (TM / 2) + im * 16 + l16;
                af[c][im] = *reinterpret_cast<const bf8_t*>(
                    &As[row * 64 + (((c * 4 + quad) ^ (row & 7)) * 8)]);
            }
            #pragma unroll
            for (int in_ = 0; in_ < 4; in_++) {
                int row = wn * 64 + in_ * 16 + l16;
                bfr[c][in_] = *reinterpret_cast<const bf8_t*>(
                    &Bs[row * 64 + (((c * 4 + quad) ^ (row & 7)) * 8)]);
            }
        }
        #pragma unroll
        for (int c = 0; c < 2; c++)
            #pragma unroll
            for (int im = 0; im < NI; im++)
                #pragma unroll
                for (int in_ = 0; in_ < 4; in_++)
                    acc[im][in_] = __builtin_amdgcn_mfma_f32_16x16x32_bf16(
                        af[c][im], bfr[c][in_], acc[im][in_], 0, 0, 0);
        __syncthreads();
    }

    #pragma unroll
    for (int im = 0; im < NI; im++) {
        #pragma unroll
        for (int in_ = 0; in_ < 4; in_++) {
            int gc  = bx * 128 + wn * 64 + in_ * 16 + l16;
            float bb = bias[gc];
            int gr0 = by * TM + wm * (TM / 2) + im * 16 + quad * 4;
            #pragma unroll
            for (int r = 0; r < 4; r++) {
                int gr  = gr0 + r;
                float v = (acc[im][in_][r] + bb) * oscale;
                size_t idx;
                if (mode == 0) {
                    idx = (size_t)gr * 1024 + gc;
                } else {
                    int b = gr >> 11, t = gr & 2047;
                    int h = gc >> 6,  d = gc & 63;
                    if (mode == 1) idx = ((size_t)(b * Hh + h) * Tt + t) * Dd + d;
                    else           idx = ((size_t)(b * Hh + h) * Dd + d) * Tt + t;
                }
                out[idx] = (OutT)v;
            }
        }
    }
}

__global__ __launch_bounds__(256) void gemm_qkv_kernel(
    const __bf16* __restrict__ A,
    const __bf16* __restrict__ WqT, const __bf16* __restrict__ WkT, const __bf16* __restrict__ WvT,
    const float* __restrict__ bq,  const float* __restrict__ bk,  const float* __restrict__ bv,
    __bf16* __restrict__ Qo, __bf16* __restrict__ Ko, __bf16* __restrict__ Vo)
{
    const __bf16* Bt; const float* bias; __bf16* out; int mode; float sc;
    if      (blockIdx.z == 0) { Bt = WqT; bias = bq; out = Qo; mode = 1; sc = 0.18033688011112042f; }
    else if (blockIdx.z == 1) { Bt = WkT; bias = bk; out = Ko; mode = 1; sc = 1.f; }
    else                      { Bt = WvT; bias = bv; out = Vo; mode = 2; sc = 1.f; }
    gemm_body<128, __bf16>(A, Bt, bias, out, mode, sc, blockIdx.x, blockIdx.y);
}

__global__ __launch_bounds__(256) void gemm_out_kernel(
    const __bf16* __restrict__ A, const __bf16* __restrict__ Bt,
    const float* __restrict__ bias, float* __restrict__ out)
{
    gemm_body<64, float>(A, Bt, bias, out, 0, 1.f, blockIdx.x, blockIdx.y);
}

// ---------------------------------------------------------------- flash attn
// grid (T/128, H, B*2), 512 threads = 8 waves. blockIdx.z = b*2 + split;
// split s handles keys [s*1024, s*1024+1024). Per 64-key tile:
//   ds_write prefetched K/V regs -> LDS; barrier; issue next-tile global
//   loads; compute (8 QK MFMA with bias C-init, exp2, P roundtrip, 8 PV
//   MFMA); barrier.  Partial O (f32) and l written to workspace; combine
//   kernel finishes (valid: fixed-max softmax partials add linearly).
__global__ __launch_bounds__(512, 8) void flash_kernel(
    const __bf16* __restrict__ Qb, const __bf16* __restrict__ Kb,
    const __bf16* __restrict__ Vb, const __bf16* __restrict__ biasb,
    float* __restrict__ Opart, float* __restrict__ Lpart)
{
    alignas(16) __shared__ __bf16 Ks[64 * 64];      // swizzled, 8KB
    alignas(16) __shared__ __bf16 Vs[64 * 64];      // 8KB
    alignas(16) __shared__ __bf16 Ps[8 * 16 * 72];  // per-wave P^T, 18KB

    int tid  = threadIdx.x;
    int lane = tid & 63;
    int wave = tid >> 6;
    int quad = lane >> 4;
    int l16  = lane & 15;
    int b    = blockIdx.z >> 1;
    int split= blockIdx.z & 1;
    int h    = blockIdx.y;
    int bh   = b * Hh + h;
    int qrow = blockIdx.x * 128 + wave * 16;
    const int kt0 = split * 1024;

    int srow = tid >> 3, sj = tid & 7;
    const __bf16* kgp = Kb + ((size_t)bh * Tt + kt0 + srow) * Dd + ((sj ^ (srow & 7)) * 8);
    const __bf16* vgp = Vb + ((size_t)bh * Dd + srow) * Tt + kt0 + ((sj ^ (srow & 7)) * 8);
    const int sdst = tid * 8;

    bf8_t qf[2];
    #pragma unroll
    for (int c = 0; c < 2; c++)
        qf[c] = *reinterpret_cast<const bf8_t*>(
            Qb + ((size_t)bh * Tt + qrow + l16) * Dd + c * 32 + quad * 8);

    const __bf16* bp = biasb + ((size_t)b * Tt + qrow + l16) * Tt + kt0 + quad * 4;

    float l_i = 0.f;
    f4_t o[4];
    #pragma unroll
    for (int d = 0; d < 4; d++) o[d] = f4_t{0.f, 0.f, 0.f, 0.f};

    __bf16* pw = Ps + wave * 16 * 72;

    // prime: tile 0 of this split into regs
    bf8_t kreg = *reinterpret_cast<const bf8_t*>(kgp);
    bf8_t vreg = *reinterpret_cast<const bf8_t*>(vgp);
    bf4_t breg[4];
    #pragma unroll
    for (int n = 0; n < 4; n++)
        breg[n] = *reinterpret_cast<const bf4_t*>(bp + n * 16);

    for (int kt = 0; kt < 1024; kt += 64) {
        *reinterpret_cast<bf8_t*>(&Ks[sdst]) = kreg;
        *reinterpret_cast<bf8_t*>(&Vs[sdst]) = vreg;
        f4_t s[4];
        #pragma unroll
        for (int n = 0; n < 4; n++)
            s[n] = f4_t{(float)breg[n][0], (float)breg[n][1],
                        (float)breg[n][2], (float)breg[n][3]};
        __syncthreads();

        // prefetch next tile (lands during compute; drained by barrier 2
        // only after a full compute span)
        int ktn = (kt + 64 < 1024) ? kt + 64 : 0;
        kreg = *reinterpret_cast<const bf8_t*>(kgp + (size_t)ktn * Dd);
        vreg = *reinterpret_cast<const bf8_t*>(vgp + ktn);
        #pragma unroll
        for (int n = 0; n < 4; n++)
            breg[n] = *reinterpret_cast<const bf4_t*>(bp + ktn + n * 16);

        // S^T = K Q^T
        #pragma unroll
        for (int c = 0; c < 2; c++)
            #pragma unroll
            for (int n = 0; n < 4; n++) {
                int krow = n * 16 + l16;
                bf8_t kf = *reinterpret_cast<const bf8_t*>(
                    &Ks[krow * 64 + (((c * 4 + quad) ^ (krow & 7)) * 8)]);
                s[n] = __builtin_amdgcn_mfma_f32_16x16x32_bf16(kf, qf[c], s[n], 0, 0, 0);
            }

        // p = exp2(s); row-sum; P^T -> LDS
        float rs = 0.f;
        #pragma unroll
        for (int n = 0; n < 4; n++) {
            bf4_t pv4;
            #pragma unroll
            for (int r = 0; r < 4; r++) {
                float p = EXP2F(s[n][r]);
                rs += p;
                pv4[r] = (__bf16)p;
            }
            *reinterpret_cast<bf4_t*>(&pw[l16 * 72 + n * 16 + quad * 4]) = pv4;
        }
        rs += __shfl_xor(rs, 16);
        rs += __shfl_xor(rs, 32);
        l_i += rs;

        // O^T += V^T @ P^T
        #pragma unroll
        for (int c = 0; c < 2; c++) {
            bf8_t pf = *reinterpret_cast<const bf8_t*>(
                &pw[l16 * 72 + c * 32 + quad * 8]);
            #pragma unroll
            for (int ds = 0; ds < 4; ds++) {
                int vrow = ds * 16 + l16;
                bf8_t vf = *reinterpret_cast<const bf8_t*>(
                    &Vs[vrow * 64 + (((c * 4 + quad) ^ (vrow & 7)) * 8)]);
                o[ds] = __builtin_amdgcn_mfma_f32_16x16x32_bf16(vf, pf, o[ds], 0, 0, 0);
            }
        }
        __syncthreads();
    }

    // write partial O (f32) and partial l
    size_t orow = ((size_t)(split * Bb + b) * Tt + qrow + l16) * 1024 + h * 64;
    #pragma unroll
    for (int ds = 0; ds < 4; ds++)
        *reinterpret_cast<f4_t*>(Opart + orow + ds * 16 + quad * 4) = o[ds];
    if (quad == 0)
        Lpart[((size_t)(split * Bb + b) * Tt + qrow + l16) * Hh + h] = l_i;
}

// ------------------------------------------------------------ split combine
// Z = (O0 + O1) / (l0 + l1), f32 partials -> bf16 Zb. 4M elems.
__global__ __launch_bounds__(256) void combine_kernel(
    const float* __restrict__ Opart, const float* __restrict__ Lpart,
    __bf16* __restrict__ Zb)
{
    const size_t NTOT = (size_t)Bb * Tt * 1024;
    size_t i = ((size_t)blockIdx.x * 256 + threadIdx.x) * 4;
    size_t row = i >> 10;            // b*T + q
    int    h   = (int)((i & 1023) >> 6);
    f4_t a = *reinterpret_cast<const f4_t*>(Opart + i);
    f4_t c = *reinterpret_cast<const f4_t*>(Opart + NTOT + i);
    float l = Lpart[row * Hh + h] + Lpart[(size_t)Bb * Tt * Hh + row * Hh + h];
    float inv = 1.f / fmaxf(l, 1e-30f);
    bf4_t ov;
    #pragma unroll
    for (int r = 0; r < 4; r++) ov[r] = (__bf16)((a[r] + c[r]) * inv);
    *reinterpret_cast<bf4_t*>(Zb + i) = ov;
}

// ---------------------------------------------------------------- launch
extern "C" void kernel_launch(void* const* d_in, const int* in_sizes, int n_in,
                              void* d_out, int out_size, void* d_ws, size_t ws_size,
                              hipStream_t stream)
{
    (void)in_sizes; (void)n_in; (void)out_size; (void)ws_size;

    const float* embed = (const float*)d_in[0];
    const int*   mask  = (const int*)d_in[1];
    const float* Wq = (const float*)d_in[2];
    const float* bq = (const float*)d_in[3];
    const float* Wk = (const float*)d_in[4];
    const float* bk = (const float*)d_in[5];
    const float* Wv = (const float*)d_in[6];
    const float* bv = (const float*)d_in[7];
    const float* Wz = (const float*)d_in[8];
    const float* bz = (const float*)d_in[9];
    float* out = (float*)d_out;

    char* ws = (char*)d_ws;
    const size_t MB = (size_t)1024 * 1024;
    __bf16* WqT = (__bf16*)(ws + 0 * MB);
    __bf16* WkT = (__bf16*)(ws + 2 * MB);
    __bf16* WvT = (__bf16*)(ws + 4 * MB);
    __bf16* WzT = (__bf16*)(ws + 6 * MB);
    __bf16* Eb  = (__bf16*)(ws + 8 * MB);
    __bf16* Qb  = (__bf16*)(ws + 16 * MB);
    __bf16* Kb  = (__bf16*)(ws + 24 * MB);
    __bf16* Vb  = (__bf16*)(ws + 32 * MB);
    __bf16* Zb  = (__bf16*)(ws + 40 * MB);
    __bf16* Mb  = (__bf16*)(ws + 48 * MB);   // bf16 bias [B,T,T] 16MB
    float*  Op  = (float*)(ws + 64 * MB);    // 2 x 16MB f32 partial O
    float*  Lp  = (float*)(ws + 96 * MB);    // 2 x 256KB f32 partial l

    convert_kernel<<<dim3(4096), 256, 0, stream>>>(embed, Eb);
    maskbias_kernel<<<dim3(8192), 256, 0, stream>>>(mask, Mb);
    transpose_kernel<<<dim3(32, 32, 4), 256, 0, stream>>>(Wq, Wk, Wv, Wz,
                                                          WqT, WkT, WvT, WzT);
    gemm_qkv_kernel<<<dim3(8, 32, 3), 256, 0, stream>>>(Eb, WqT, WkT, WvT,
                                                        bq, bk, bv, Qb, Kb, Vb);
    flash_kernel<<<dim3(16, Hh, Bb * 2), 512, 0, stream>>>(Qb, Kb, Vb, Mb, Op, Lp);
    combine_kernel<<<dim3(4096), 256, 0, stream>>>(Op, Lp, Zb);
    gemm_out_kernel<<<dim3(8, 64, 1), 256, 0, stream>>>(Zb, WzT, bz, out);
}

// Round 7
// 238.240 us; speedup vs baseline: 1.1863x; 1.1863x over previous
//
#include <hip/hip_runtime.h>
#include <hip/hip_bf16.h>

// B=2, T=2048, E=1024, H=16, D=64. Inputs f32 (+ int32 mask), output f32.
// Internal bf16 MFMA pipeline. Flash (round-5 structure): S^T formulation,
// fixed-max exp2 softmax, q-tile 128, register-staged double-buffered LDS,
// ONE barrier per K-tile (prefetch issued after the barrier), int32 mask
// read directly and injected via MFMA C-operand init (cndmask).

typedef __bf16 bf8_t  __attribute__((ext_vector_type(8)));
typedef __bf16 bf4_t  __attribute__((ext_vector_type(4)));
typedef float  f4_t   __attribute__((ext_vector_type(4)));

constexpr int Bb = 2, Tt = 2048, Hh = 16, Dd = 64;

#define ASYNC16(g, l)                                                        \
    __builtin_amdgcn_global_load_lds(                                        \
        (const __attribute__((address_space(1))) void*)(g),                  \
        (__attribute__((address_space(3))) void*)(l), 16, 0, 0)

#if __has_builtin(__builtin_amdgcn_exp2f)
#define EXP2F(x) __builtin_amdgcn_exp2f(x)
#else
#define EXP2F(x) exp2f(x)
#endif

// ------------------------------------------------------------ f32 -> bf16
__global__ __launch_bounds__(256) void convert_kernel(
    const float* __restrict__ in, __bf16* __restrict__ out)
{
    int i = (blockIdx.x * 256 + threadIdx.x) * 4;
    float4 v = *reinterpret_cast<const float4*>(in + i);
    bf4_t o = {(__bf16)v.x, (__bf16)v.y, (__bf16)v.z, (__bf16)v.w};
    *reinterpret_cast<bf4_t*>(out + i) = o;
}

// ------------------------------------------------------------ transpose+cast
__global__ __launch_bounds__(256) void transpose_kernel(
    const float* __restrict__ w0, const float* __restrict__ w1,
    const float* __restrict__ w2, const float* __restrict__ w3,
    __bf16* __restrict__ o0, __bf16* __restrict__ o1,
    __bf16* __restrict__ o2, __bf16* __restrict__ o3)
{
    const float* in; __bf16* out;
    switch (blockIdx.z) {
        case 0: in = w0; out = o0; break;
        case 1: in = w1; out = o1; break;
        case 2: in = w2; out = o2; break;
        default: in = w3; out = o3; break;
    }
    __shared__ float t[32][33];
    int x  = threadIdx.x & 31;
    int y0 = threadIdx.x >> 5;
    int bx = blockIdx.x * 32;
    int by = blockIdx.y * 32;
    #pragma unroll
    for (int i = 0; i < 4; i++) {
        int y = y0 + i * 8;
        t[y][x] = in[(size_t)(by + y) * 1024 + bx + x];
    }
    __syncthreads();
    #pragma unroll
    for (int i = 0; i < 4; i++) {
        int y = y0 + i * 8;
        out[(size_t)(bx + y) * 1024 + by + x] = (__bf16)t[x][y];
    }
}

// ---------------------------------------------------------------- GEMM body
// mode 0: out[gr*1024+gc] f32;  mode 1: [B,H,T,D] bf16;
// mode 2: [B,H,D,T] bf16 with vectorized bf16x4 stores along t.
template <int TM, typename OutT>
__device__ __forceinline__ void gemm_body(const __bf16* __restrict__ A,
                                          const __bf16* __restrict__ Bt,
                                          const float* __restrict__ bias,
                                          OutT* __restrict__ out,
                                          int mode, float oscale, int bx, int by)
{
    constexpr int NI = TM / 32;
    alignas(16) __shared__ __bf16 As[TM * 64];
    alignas(16) __shared__ __bf16 Bs[128 * 64];

    int tid  = threadIdx.x;
    int lane = tid & 63;
    int quad = lane >> 4;
    int l16  = lane & 15;
    int wave = tid >> 6;
    int wm   = wave >> 1, wn = wave & 1;

    f4_t acc[NI][4];
    #pragma unroll
    for (int i = 0; i < NI; i++)
        #pragma unroll
        for (int j = 0; j < 4; j++)
            acc[i][j] = f4_t{0.f, 0.f, 0.f, 0.f};

    for (int kt = 0; kt < 1024; kt += 64) {
        #pragma unroll
        for (int i = 0; i < TM / 32; i++) {
            int c   = tid + 256 * i;
            int row = c >> 3, j = c & 7;
            ASYNC16(A + (size_t)(by * TM + row) * 1024 + kt + ((j ^ (row & 7)) * 8),
                    &As[c * 8]);
        }
        #pragma unroll
        for (int i = 0; i < 4; i++) {
            int c   = tid + 256 * i;
            int row = c >> 3, j = c & 7;
            ASYNC16(Bt + (size_t)(bx * 128 + row) * 1024 + kt + ((j ^ (row & 7)) * 8),
                    &Bs[c * 8]);
        }
        __syncthreads();

        bf8_t af[2][NI], bfr[2][4];
        #pragma unroll
        for (int c = 0; c < 2; c++) {
            #pragma unroll
            for (int im = 0; im < NI; im++) {
                int row = wm * (TM / 2) + im * 16 + l16;
                af[c][im] = *reinterpret_cast<const bf8_t*>(
                    &As[row * 64 + (((c * 4 + quad) ^ (row & 7)) * 8)]);
            }
            #pragma unroll
            for (int in_ = 0; in_ < 4; in_++) {
                int row = wn * 64 + in_ * 16 + l16;
                bfr[c][in_] = *reinterpret_cast<const bf8_t*>(
                    &Bs[row * 64 + (((c * 4 + quad) ^ (row & 7)) * 8)]);
            }
        }
        #pragma unroll
        for (int c = 0; c < 2; c++)
            #pragma unroll
            for (int im = 0; im < NI; im++)
                #pragma unroll
                for (int in_ = 0; in_ < 4; in_++)
                    acc[im][in_] = __builtin_amdgcn_mfma_f32_16x16x32_bf16(
                        af[c][im], bfr[c][in_], acc[im][in_], 0, 0, 0);
        __syncthreads();
    }

    #pragma unroll
    for (int im = 0; im < NI; im++) {
        #pragma unroll
        for (int in_ = 0; in_ < 4; in_++) {
            int gc  = bx * 128 + wn * 64 + in_ * 16 + l16;
            float bb = bias[gc];
            int gr0 = by * TM + wm * (TM / 2) + im * 16 + quad * 4;
            if (mode == 2) {
                // lane's 4 acc regs = 4 consecutive t at fixed (h,d)
                int b = gr0 >> 11, t0 = gr0 & 2047;
                int h = gc >> 6,  d = gc & 63;
                bf4_t ov;
                #pragma unroll
                for (int r = 0; r < 4; r++)
                    ov[r] = (__bf16)(acc[im][in_][r] + bb);
                *reinterpret_cast<bf4_t*>(
                    (__bf16*)out + ((size_t)(b * Hh + h) * Dd + d) * Tt + t0) = ov;
            } else {
                #pragma unroll
                for (int r = 0; r < 4; r++) {
                    int gr  = gr0 + r;
                    float v = (acc[im][in_][r] + bb) * oscale;
                    size_t idx;
                    if (mode == 0) {
                        idx = (size_t)gr * 1024 + gc;
                    } else {
                        int b = gr >> 11, t = gr & 2047;
                        int h = gc >> 6,  d = gc & 63;
                        idx = ((size_t)(b * Hh + h) * Tt + t) * Dd + d;
                    }
                    out[idx] = (OutT)v;
                }
            }
        }
    }
}

__global__ __launch_bounds__(256) void gemm_qkv_kernel(
    const __bf16* __restrict__ A,
    const __bf16* __restrict__ WqT, const __bf16* __restrict__ WkT, const __bf16* __restrict__ WvT,
    const float* __restrict__ bq,  const float* __restrict__ bk,  const float* __restrict__ bv,
    __bf16* __restrict__ Qo, __bf16* __restrict__ Ko, __bf16* __restrict__ Vo)
{
    const __bf16* Bt; const float* bias; __bf16* out; int mode; float sc;
    // Q carries 0.125 * log2(e) so flash softmax runs in exp2 domain.
    if      (blockIdx.z == 0) { Bt = WqT; bias = bq; out = Qo; mode = 1; sc = 0.18033688011112042f; }
    else if (blockIdx.z == 1) { Bt = WkT; bias = bk; out = Ko; mode = 1; sc = 1.f; }
    else                      { Bt = WvT; bias = bv; out = Vo; mode = 2; sc = 1.f; }
    gemm_body<128, __bf16>(A, Bt, bias, out, mode, sc, blockIdx.x, blockIdx.y);
}

__global__ __launch_bounds__(256) void gemm_out_kernel(
    const __bf16* __restrict__ A, const __bf16* __restrict__ Bt,
    const float* __restrict__ bias, float* __restrict__ out)
{
    gemm_body<64, float>(A, Bt, bias, out, 0, 1.f, blockIdx.x, blockIdx.y);
}

// ---------------------------------------------------------------- flash attn
// grid (T/128, H, B), 512 threads = 8 waves; wave w owns 16 queries over all
// keys. Round-5 structure: dbuf LDS, one barrier/iter, reg-staged K/V,
// prefetch after the barrier. Mask read as int4, folded into C-operand init.
__global__ __launch_bounds__(512, 4) void flash_kernel(
    const __bf16* __restrict__ Qb, const __bf16* __restrict__ Kb,
    const __bf16* __restrict__ Vb, const int* __restrict__ mask,
    __bf16* __restrict__ Zb)
{
    alignas(16) __shared__ __bf16 Ks[2][64 * 64];   // swizzled, 8KB each
    alignas(16) __shared__ __bf16 Vs[2][64 * 64];
    alignas(16) __shared__ __bf16 Ps[8 * 16 * 72];  // per-wave P^T, 18KB

    int tid  = threadIdx.x;
    int lane = tid & 63;
    int wave = tid >> 6;
    int quad = lane >> 4;
    int l16  = lane & 15;
    int b = blockIdx.z, h = blockIdx.y;
    int bh = b * Hh + h;
    int qrow = blockIdx.x * 128 + wave * 16;

    int srow = tid >> 3, sj = tid & 7;
    const __bf16* kgp = Kb + ((size_t)bh * Tt + srow) * Dd + ((sj ^ (srow & 7)) * 8);
    const __bf16* vgp = Vb + ((size_t)bh * Dd + srow) * Tt + ((sj ^ (srow & 7)) * 8);
    const int sdst = tid * 8;

    bf8_t qf[2];
    #pragma unroll
    for (int c = 0; c < 2; c++)
        qf[c] = *reinterpret_cast<const bf8_t*>(
            Qb + ((size_t)bh * Tt + qrow + l16) * Dd + c * 32 + quad * 8);

    // mask row for this lane's query; col = kt + n*16 + quad*4 (int4-aligned)
    const int* mp = mask + ((size_t)b * Tt + qrow + l16) * Tt + quad * 4;

    float l_i = 0.f;
    f4_t o[4];
    #pragma unroll
    for (int d = 0; d < 4; d++) o[d] = f4_t{0.f, 0.f, 0.f, 0.f};

    __bf16* pw = Ps + wave * 16 * 72;

    // prime: tile 0 into regs
    bf8_t kreg = *reinterpret_cast<const bf8_t*>(kgp);
    bf8_t vreg = *reinterpret_cast<const bf8_t*>(vgp);
    int4 ireg[4];
    #pragma unroll
    for (int n = 0; n < 4; n++)
        ireg[n] = *reinterpret_cast<const int4*>(mp + n * 16);

    for (int kt = 0; kt < Tt; kt += 64) {
        int par = (kt >> 6) & 1;
        *reinterpret_cast<bf8_t*>(&Ks[par][sdst]) = kreg;
        *reinterpret_cast<bf8_t*>(&Vs[par][sdst]) = vreg;
        // capture mask into accumulator init before regs are reloaded
        f4_t s[4];
        #pragma unroll
        for (int n = 0; n < 4; n++)
            s[n] = f4_t{ireg[n].x ? 0.f : -1e30f, ireg[n].y ? 0.f : -1e30f,
                        ireg[n].z ? 0.f : -1e30f, ireg[n].w ? 0.f : -1e30f};
        __syncthreads();

        // prefetch next tile (issued after barrier -> not drained by it)
        int ktn = (kt + 64 < Tt) ? kt + 64 : 0;
        kreg = *reinterpret_cast<const bf8_t*>(kgp + (size_t)ktn * Dd);
        vreg = *reinterpret_cast<const bf8_t*>(vgp + ktn);
        #pragma unroll
        for (int n = 0; n < 4; n++)
            ireg[n] = *reinterpret_cast<const int4*>(mp + ktn + n * 16);

        // S^T = K Q^T : 4 key-subtiles x 2 d-chunks
        #pragma unroll
        for (int c = 0; c < 2; c++)
            #pragma unroll
            for (int n = 0; n < 4; n++) {
                int krow = n * 16 + l16;
                bf8_t kf = *reinterpret_cast<const bf8_t*>(
                    &Ks[par][krow * 64 + (((c * 4 + quad) ^ (krow & 7)) * 8)]);
                s[n] = __builtin_amdgcn_mfma_f32_16x16x32_bf16(kf, qf[c], s[n], 0, 0, 0);
            }

        // p = exp2(s); row-sum via 2 shuffles; P^T -> LDS
        float rs = 0.f;
        #pragma unroll
        for (int n = 0; n < 4; n++) {
            bf4_t pv4;
            #pragma unroll
            for (int r = 0; r < 4; r++) {
                float p = EXP2F(s[n][r]);
                rs += p;
                pv4[r] = (__bf16)p;
            }
            *reinterpret_cast<bf4_t*>(&pw[l16 * 72 + n * 16 + quad * 4]) = pv4;
        }
        rs += __shfl_xor(rs, 16);
        rs += __shfl_xor(rs, 32);
        l_i += rs;

        // O^T += V^T @ P^T over 64 keys (2 chunks)
        #pragma unroll
        for (int c = 0; c < 2; c++) {
            bf8_t pf = *reinterpret_cast<const bf8_t*>(
                &pw[l16 * 72 + c * 32 + quad * 8]);
            #pragma unroll
            for (int ds = 0; ds < 4; ds++) {
                int vrow = ds * 16 + l16;
                bf8_t vf = *reinterpret_cast<const bf8_t*>(
                    &Vs[par][vrow * 64 + (((c * 4 + quad) ^ (vrow & 7)) * 8)]);
                o[ds] = __builtin_amdgcn_mfma_f32_16x16x32_bf16(vf, pf, o[ds], 0, 0, 0);
            }
        }
        // no trailing barrier: next iter writes the other buffer.
    }

    float inv = 1.f / fmaxf(l_i, 1e-30f);
    size_t zrow = ((size_t)b * Tt + qrow + l16) * 1024 + h * 64;
    #pragma unroll
    for (int ds = 0; ds < 4; ds++) {
        bf4_t ov;
        #pragma unroll
        for (int r = 0; r < 4; r++) ov[r] = (__bf16)(o[ds][r] * inv);
        *reinterpret_cast<bf4_t*>(Zb + zrow + ds * 16 + quad * 4) = ov;
    }
}

// ---------------------------------------------------------------- launch
extern "C" void kernel_launch(void* const* d_in, const int* in_sizes, int n_in,
                              void* d_out, int out_size, void* d_ws, size_t ws_size,
                              hipStream_t stream)
{
    (void)in_sizes; (void)n_in; (void)out_size; (void)ws_size;

    const float* embed = (const float*)d_in[0];
    const int*   mask  = (const int*)d_in[1];
    const float* Wq = (const float*)d_in[2];
    const float* bq = (const float*)d_in[3];
    const float* Wk = (const float*)d_in[4];
    const float* bk = (const float*)d_in[5];
    const float* Wv = (const float*)d_in[6];
    const float* bv = (const float*)d_in[7];
    const float* Wz = (const float*)d_in[8];
    const float* bz = (const float*)d_in[9];
    float* out = (float*)d_out;

    char* ws = (char*)d_ws;
    const size_t MB = (size_t)1024 * 1024;
    __bf16* WqT = (__bf16*)(ws + 0 * MB);
    __bf16* WkT = (__bf16*)(ws + 2 * MB);
    __bf16* WvT = (__bf16*)(ws + 4 * MB);
    __bf16* WzT = (__bf16*)(ws + 6 * MB);
    __bf16* Eb  = (__bf16*)(ws + 8 * MB);
    __bf16* Qb  = (__bf16*)(ws + 16 * MB);
    __bf16* Kb  = (__bf16*)(ws + 24 * MB);
    __bf16* Vb  = (__bf16*)(ws + 32 * MB);
    __bf16* Zb  = (__bf16*)(ws + 40 * MB);   // total 48MB

    convert_kernel<<<dim3(4096), 256, 0, stream>>>(embed, Eb);
    transpose_kernel<<<dim3(32, 32, 4), 256, 0, stream>>>(Wq, Wk, Wv, Wz,
                                                          WqT, WkT, WvT, WzT);
    gemm_qkv_kernel<<<dim3(8, 32, 3), 256, 0, stream>>>(Eb, WqT, WkT, WvT,
                                                        bq, bk, bv, Qb, Kb, Vb);
    flash_kernel<<<dim3(16, Hh, Bb), 512, 0, stream>>>(Qb, Kb, Vb, mask, Zb);
    gemm_out_kernel<<<dim3(8, 64, 1), 256, 0, stream>>>(Zb, WzT, bz, out);
}